// Round 1
// baseline (126.780 us; speedup 1.0000x reference)
//
#include <hip/hip_runtime.h>
#include <hip/hip_bf16.h>

// Problem constants (from reference setup_inputs):
//   bs=8, Na=128, Nc=256, CS=3, D=64, H=64, Z=8, NT=3, NET=9
// Output 0: logpi (8,256,8,8,8) f32 = 1048576 elems
// Output 1: z meshgrid (8,8,8,3) = 1536 elems (written as float values)

#define BS   8
#define NA   128
#define NC   256
#define DIM  64
#define ZZ   8

// ---------------------------------------------------------------------------
// Kernel A: node MLP for every (b,n), only the node's own type.
// node_factor[b,n,z] = (relu(relu(enc@W0[t]+b0)@W1[t]+b1)@W2[t]+b2)[z]
// grid = bs*Na blocks, 64 threads (1 wave)
// ---------------------------------------------------------------------------
__global__ __launch_bounds__(64) void node_mlp_kernel(
    const int* __restrict__ nt, const float* __restrict__ enc,
    const float* __restrict__ W0, const float* __restrict__ b0,
    const float* __restrict__ W1, const float* __restrict__ b1,
    const float* __restrict__ W2, const float* __restrict__ b2,
    float* __restrict__ nf /* (BS,NA,ZZ) */) {
  const int blk  = blockIdx.x;      // b*NA + n
  const int lane = threadIdx.x;     // 0..63
  const int t = nt[blk];

  __shared__ float e[DIM];
  __shared__ float h[DIM];

  e[lane] = enc[blk * DIM + lane];
  __syncthreads();

  // layer 0
  float acc = b0[t * DIM + lane];
  {
    const float* w = W0 + t * DIM * DIM;
#pragma unroll
    for (int d = 0; d < DIM; ++d) acc = fmaf(e[d], w[d * DIM + lane], acc);
  }
  acc = fmaxf(acc, 0.f);
  h[lane] = acc;
  __syncthreads();

  // layer 1
  acc = b1[t * DIM + lane];
  {
    const float* w = W1 + t * DIM * DIM;
#pragma unroll
    for (int d = 0; d < DIM; ++d) acc = fmaf(h[d], w[d * DIM + lane], acc);
  }
  acc = fmaxf(acc, 0.f);
  __syncthreads();
  e[lane] = acc;   // reuse e as h1
  __syncthreads();

  // layer 2: 8 outputs, lanes 0..7
  if (lane < ZZ) {
    float a2 = b2[t * ZZ + lane];
    const float* w2 = W2 + t * DIM * ZZ;
#pragma unroll
    for (int k = 0; k < DIM; ++k) a2 = fmaf(e[k], w2[k * ZZ + lane], a2);
    nf[blk * ZZ + lane] = a2;
  }
}

// ---------------------------------------------------------------------------
// Kernel B: one block per clique. Gathers the 3 node factors, computes the 3
// edge MLPs on demand (only the selected edge type), assembles logpi.
// grid = bs*Nc blocks, 64 threads (1 wave)
// ---------------------------------------------------------------------------
__global__ __launch_bounds__(64) void clique_kernel(
    const int* __restrict__ nt, const int* __restrict__ cni,
    const float* __restrict__ edge_enc, const float* __restrict__ nf,
    const float* __restrict__ eW0, const float* __restrict__ eb0,
    const float* __restrict__ eW1, const float* __restrict__ eb1,
    const float* __restrict__ eW2, const float* __restrict__ eb2,
    float* __restrict__ out) {
  const int blk  = blockIdx.x;     // b*NC + c
  const int lane = threadIdx.x;    // 0..63
  const int b = blk >> 8;

  __shared__ float e[DIM];
  __shared__ float h[DIM];
  __shared__ float nfs[3][ZZ];
  __shared__ float ef[3][DIM];
  __shared__ int   idxs[3];

  if (lane < 3) {
    int v = cni[blk * 3 + lane];
    if (v < 0 || v >= NA) v = NA;   // pad row -> zero factors
    idxs[lane] = v;
  }
  __syncthreads();

  // gather node factors (lanes 0..23)
  if (lane < 3 * ZZ) {
    const int i = lane >> 3, z = lane & 7;
    const int v = idxs[i];
    nfs[i][z] = (v < NA) ? nf[(b * NA + v) * ZZ + z] : 0.f;
  }

  // the 3 pairs (slot_i < slot_j): (0,1),(0,2),(1,2)
  const int pi[3] = {0, 0, 1};
  const int pj[3] = {1, 2, 2};

  for (int p = 0; p < 3; ++p) {
    const int ia = idxs[pi[p]];   // row
    const int jb = idxs[pj[p]];   // col
    if (ia >= NA || jb >= NA) {   // block-uniform condition (shared idxs)
      ef[p][lane] = 0.f;
      continue;
    }
    const int t = nt[b * NA + jb] * 3 + nt[b * NA + ia];

    __syncthreads();  // previous iteration done reading e
    e[lane] = edge_enc[((b * NA + ia) * NA + jb) * DIM + lane];
    __syncthreads();

    // layer 0
    float acc = eb0[t * DIM + lane];
    {
      const float* w = eW0 + t * DIM * DIM;
#pragma unroll
      for (int d = 0; d < DIM; ++d) acc = fmaf(e[d], w[d * DIM + lane], acc);
    }
    acc = fmaxf(acc, 0.f);
    h[lane] = acc;
    __syncthreads();

    // layer 1
    acc = eb1[t * DIM + lane];
    {
      const float* w = eW1 + t * DIM * DIM;
#pragma unroll
      for (int d = 0; d < DIM; ++d) acc = fmaf(h[d], w[d * DIM + lane], acc);
    }
    acc = fmaxf(acc, 0.f);
    __syncthreads();
    e[lane] = acc;   // h1 lives in e now
    __syncthreads();

    // layer 2 (64 outputs, no relu)
    acc = eb2[t * DIM + lane];
    {
      const float* w = eW2 + t * DIM * DIM;
#pragma unroll
      for (int d = 0; d < DIM; ++d) acc = fmaf(e[d], w[d * DIM + lane], acc);
    }
    ef[p][lane] = acc;
  }
  __syncthreads();

  // assembly: lane = z1*8+z2, loop over z0 (coalesced 256B stores)
  const int z1 = lane >> 3, z2 = lane & 7;
  const float base = nfs[1][z1] + nfs[2][z2] + ef[2][z1 * ZZ + z2];
  float* o = out + blk * (ZZ * ZZ * ZZ);
#pragma unroll
  for (int z0 = 0; z0 < ZZ; ++z0) {
    o[z0 * 64 + lane] = base + nfs[0][z0] + ef[0][z0 * ZZ + z1] + ef[1][z0 * ZZ + z2];
  }
}

// ---------------------------------------------------------------------------
// Kernel C: z = meshgrid(arange(8),arange(8),arange(8),'ij') stacked -> (8,8,8,3)
// written as float values (harness reads the whole out buffer as f32).
// ---------------------------------------------------------------------------
__global__ __launch_bounds__(256) void z_kernel(float* __restrict__ out) {
  const int i = blockIdx.x * 256 + threadIdx.x;  // 0..1535
  if (i < ZZ * ZZ * ZZ * 3) {
    const int k = i % 3;
    const int r = i / 3;               // z0*64 + z1*8 + z2
    const int z2 = r & 7, z1 = (r >> 3) & 7, z0 = r >> 6;
    const int v = (k == 0) ? z0 : ((k == 1) ? z1 : z2);
    out[BS * NC * ZZ * ZZ * ZZ + i] = (float)v;
  }
}

extern "C" void kernel_launch(void* const* d_in, const int* in_sizes, int n_in,
                              void* d_out, int out_size, void* d_ws, size_t ws_size,
                              hipStream_t stream) {
  const int*   node_types = (const int*)  d_in[0];
  const float* node_enc   = (const float*)d_in[1];
  const float* edge_enc   = (const float*)d_in[2];
  // d_in[3] clique_index  : unused by the reference
  const int*   cni        = (const int*)  d_in[4];
  // d_in[5] clique_order_index : unused by the reference
  const float* nW0 = (const float*)d_in[6];
  const float* nb0 = (const float*)d_in[7];
  const float* nW1 = (const float*)d_in[8];
  const float* nb1 = (const float*)d_in[9];
  const float* nW2 = (const float*)d_in[10];
  const float* nb2 = (const float*)d_in[11];
  const float* eW0 = (const float*)d_in[12];
  const float* eb0 = (const float*)d_in[13];
  const float* eW1 = (const float*)d_in[14];
  const float* eb1 = (const float*)d_in[15];
  const float* eW2 = (const float*)d_in[16];
  const float* eb2 = (const float*)d_in[17];

  float* out = (float*)d_out;
  float* node_factor = (float*)d_ws;   // BS*NA*ZZ = 8192 floats = 32 KB

  node_mlp_kernel<<<BS * NA, 64, 0, stream>>>(
      node_types, node_enc, nW0, nb0, nW1, nb1, nW2, nb2, node_factor);

  clique_kernel<<<BS * NC, 64, 0, stream>>>(
      node_types, cni, edge_enc, node_factor,
      eW0, eb0, eW1, eb1, eW2, eb2, out);

  z_kernel<<<(ZZ * ZZ * ZZ * 3 + 255) / 256, 256, 0, stream>>>(out);
}

// Round 2
// 125.601 us; speedup vs baseline: 1.0094x; 1.0094x over previous
//
#include <hip/hip_runtime.h>
#include <hip/hip_bf16.h>

// Problem constants: bs=8, Na=128, Nc=256, CS=3, D=H=64, Z=8, NT=3, NET=9
// Output 0: logpi (8,256,8,8,8) f32 = 1048576 elems
// Output 1: z meshgrid (8,8,8,3) -> 1536 elems (float values)

#define BS   8
#define NA   128
#define NC   256
#define DIM  64
#define ZZ   8

// ws layout: [0, 32KB)  node_factor (8*128*8 f32)
//            [32KB, +1.5MB) ef buffer (6144 pairs * 64 f32)
#define WS_EF_OFF (BS * NA * ZZ)

// ---------------------------------------------------------------------------
// Kernel A: node MLP, one block (256 thr, split-K x4) per (b,n).
// ---------------------------------------------------------------------------
__global__ __launch_bounds__(256) void node_mlp_kernel(
    const int* __restrict__ nt, const float* __restrict__ enc,
    const float* __restrict__ W0, const float* __restrict__ b0,
    const float* __restrict__ W1, const float* __restrict__ b1,
    const float* __restrict__ W2, const float* __restrict__ b2,
    float* __restrict__ nf) {
  const int blk = blockIdx.x;          // b*NA + n
  const int tid = threadIdx.x;
  const int j = tid & 63, s = tid >> 6;  // wave s handles K-slice s
  const int t = nt[blk];

  __shared__ float e[DIM];
  __shared__ float h[DIM];
  __shared__ float red[4][DIM];
  __shared__ float red2[8][ZZ];

  if (tid < DIM) e[tid] = enc[blk * DIM + tid];
  __syncthreads();

  // layer 0: e -> h (relu)
  {
    float a = 0.f;
    const float* w = W0 + t * DIM * DIM + s * 16 * DIM + j;
#pragma unroll
    for (int k = 0; k < 16; ++k) a = fmaf(e[s * 16 + k], w[k * DIM], a);
    red[s][j] = a;
  }
  __syncthreads();
  if (s == 0) {
    float v = red[0][j] + red[1][j] + red[2][j] + red[3][j] + b0[t * DIM + j];
    h[j] = fmaxf(v, 0.f);
  }
  __syncthreads();

  // layer 1: h -> e (relu)
  {
    float a = 0.f;
    const float* w = W1 + t * DIM * DIM + s * 16 * DIM + j;
#pragma unroll
    for (int k = 0; k < 16; ++k) a = fmaf(h[s * 16 + k], w[k * DIM], a);
    red[s][j] = a;
  }
  __syncthreads();
  if (s == 0) {
    float v = red[0][j] + red[1][j] + red[2][j] + red[3][j] + b1[t * DIM + j];
    e[j] = fmaxf(v, 0.f);
  }
  __syncthreads();

  // layer 2: e (64) -> nf (8); threads 0..63, split-K x8
  if (tid < DIM) {
    const int j2 = tid & 7, s2 = tid >> 3;   // s2: 0..7
    float a = 0.f;
    const float* w = W2 + t * DIM * ZZ + s2 * 8 * ZZ + j2;
#pragma unroll
    for (int k = 0; k < 8; ++k) a = fmaf(e[s2 * 8 + k], w[k * ZZ], a);
    red2[s2][j2] = a;
  }
  __syncthreads();
  if (tid < ZZ) {
    float v = b2[t * ZZ + tid];
#pragma unroll
    for (int s2 = 0; s2 < 8; ++s2) v += red2[s2][tid];
    nf[blk * ZZ + tid] = v;
  }
}

// ---------------------------------------------------------------------------
// Kernel B: edge MLP, one block (256 thr, split-K x4) per (clique, pair).
// Writes ef[pairIdx][64] to ws.
// ---------------------------------------------------------------------------
__global__ __launch_bounds__(256) void edge_mlp_kernel(
    const int* __restrict__ nt, const int* __restrict__ cni,
    const float* __restrict__ edge_enc,
    const float* __restrict__ eW0, const float* __restrict__ eb0,
    const float* __restrict__ eW1, const float* __restrict__ eb1,
    const float* __restrict__ eW2, const float* __restrict__ eb2,
    float* __restrict__ ef_out) {
  const int blk = blockIdx.x;            // clique*3 + pair
  const int tid = threadIdx.x;
  const int j = tid & 63, s = tid >> 6;
  const int clique = blk / 3, pair = blk - clique * 3;
  const int b = clique >> 8;

  // pairs (slot_i, slot_j): (0,1),(0,2),(1,2)
  const int pi = (pair == 2) ? 1 : 0;
  const int pj = (pair == 0) ? 1 : 2;

  __shared__ int idxs[2];
  __shared__ float e[DIM];
  __shared__ float h[DIM];
  __shared__ float red[4][DIM];

  if (tid == 0) {
    int va = cni[clique * 3 + pi];
    int vb = cni[clique * 3 + pj];
    idxs[0] = (va < 0 || va >= NA) ? NA : va;
    idxs[1] = (vb < 0 || vb >= NA) ? NA : vb;
  }
  __syncthreads();
  const int ia = idxs[0], jb = idxs[1];

  if (ia >= NA || jb >= NA) {          // uniform across block
    if (tid < DIM) ef_out[blk * DIM + tid] = 0.f;
    return;
  }
  const int t = nt[b * NA + jb] * 3 + nt[b * NA + ia];

  if (tid < DIM) e[tid] = edge_enc[((b * NA + ia) * NA + jb) * DIM + tid];
  __syncthreads();

  // layer 0: e -> h (relu)
  {
    float a = 0.f;
    const float* w = eW0 + t * DIM * DIM + s * 16 * DIM + j;
#pragma unroll
    for (int k = 0; k < 16; ++k) a = fmaf(e[s * 16 + k], w[k * DIM], a);
    red[s][j] = a;
  }
  __syncthreads();
  if (s == 0) {
    float v = red[0][j] + red[1][j] + red[2][j] + red[3][j] + eb0[t * DIM + j];
    h[j] = fmaxf(v, 0.f);
  }
  __syncthreads();

  // layer 1: h -> e (relu)
  {
    float a = 0.f;
    const float* w = eW1 + t * DIM * DIM + s * 16 * DIM + j;
#pragma unroll
    for (int k = 0; k < 16; ++k) a = fmaf(h[s * 16 + k], w[k * DIM], a);
    red[s][j] = a;
  }
  __syncthreads();
  if (s == 0) {
    float v = red[0][j] + red[1][j] + red[2][j] + red[3][j] + eb1[t * DIM + j];
    e[j] = fmaxf(v, 0.f);
  }
  __syncthreads();

  // layer 2: e -> ef (no relu), store to ws
  {
    float a = 0.f;
    const float* w = eW2 + t * DIM * DIM + s * 16 * DIM + j;
#pragma unroll
    for (int k = 0; k < 16; ++k) a = fmaf(e[s * 16 + k], w[k * DIM], a);
    red[s][j] = a;
  }
  __syncthreads();
  if (s == 0) {
    ef_out[blk * DIM + j] =
        red[0][j] + red[1][j] + red[2][j] + red[3][j] + eb2[t * DIM + j];
  }
}

// ---------------------------------------------------------------------------
// Kernel C: assembly. One wave per clique; also writes the z meshgrid tail.
// ---------------------------------------------------------------------------
__global__ __launch_bounds__(64) void assemble_kernel(
    const int* __restrict__ cni, const float* __restrict__ nf,
    const float* __restrict__ ef_in, float* __restrict__ out) {
  const int blk = blockIdx.x;          // b*NC + c
  const int lane = threadIdx.x;
  const int b = blk >> 8;

  __shared__ int idxs[3];
  __shared__ float nfs[3][ZZ];
  __shared__ float ef[3][DIM];

  if (lane < 3) {
    int v = cni[blk * 3 + lane];
    idxs[lane] = (v < 0 || v >= NA) ? NA : v;
  }
  __syncthreads();
  if (lane < 3 * ZZ) {
    const int i = lane >> 3, z = lane & 7;
    const int v = idxs[i];
    nfs[i][z] = (v < NA) ? nf[(b * NA + v) * ZZ + z] : 0.f;
  }
#pragma unroll
  for (int p = 0; p < 3; ++p) ef[p][lane] = ef_in[(blk * 3 + p) * DIM + lane];
  __syncthreads();

  const int z1 = lane >> 3, z2 = lane & 7;
  const float base = nfs[1][z1] + nfs[2][z2] + ef[2][z1 * ZZ + z2];
  float* o = out + blk * (ZZ * ZZ * ZZ);
#pragma unroll
  for (int z0 = 0; z0 < ZZ; ++z0) {
    o[z0 * 64 + lane] = base + nfs[0][z0] + ef[0][z0 * ZZ + z1] + ef[1][z0 * ZZ + z2];
  }

  // z meshgrid tail: 1536 elems = 24 blocks * 64 lanes
  if (blk < 24) {
    const int i = blk * 64 + lane;
    const int k = i % 3;
    const int r = i / 3;               // z0*64 + z1*8 + z2
    const int zz2 = r & 7, zz1 = (r >> 3) & 7, zz0 = r >> 6;
    const int v = (k == 0) ? zz0 : ((k == 1) ? zz1 : zz2);
    out[BS * NC * ZZ * ZZ * ZZ + i] = (float)v;
  }
}

extern "C" void kernel_launch(void* const* d_in, const int* in_sizes, int n_in,
                              void* d_out, int out_size, void* d_ws, size_t ws_size,
                              hipStream_t stream) {
  const int*   node_types = (const int*)  d_in[0];
  const float* node_enc   = (const float*)d_in[1];
  const float* edge_enc   = (const float*)d_in[2];
  const int*   cni        = (const int*)  d_in[4];
  const float* nW0 = (const float*)d_in[6];
  const float* nb0 = (const float*)d_in[7];
  const float* nW1 = (const float*)d_in[8];
  const float* nb1 = (const float*)d_in[9];
  const float* nW2 = (const float*)d_in[10];
  const float* nb2 = (const float*)d_in[11];
  const float* eW0 = (const float*)d_in[12];
  const float* eb0 = (const float*)d_in[13];
  const float* eW1 = (const float*)d_in[14];
  const float* eb1 = (const float*)d_in[15];
  const float* eW2 = (const float*)d_in[16];
  const float* eb2 = (const float*)d_in[17];

  float* out = (float*)d_out;
  float* node_factor = (float*)d_ws;
  float* ef_buf = (float*)d_ws + WS_EF_OFF;

  node_mlp_kernel<<<BS * NA, 256, 0, stream>>>(
      node_types, node_enc, nW0, nb0, nW1, nb1, nW2, nb2, node_factor);

  edge_mlp_kernel<<<BS * NC * 3, 256, 0, stream>>>(
      node_types, cni, edge_enc, eW0, eb0, eW1, eb1, eW2, eb2, ef_buf);

  assemble_kernel<<<BS * NC, 64, 0, stream>>>(cni, node_factor, ef_buf, out);
}